// Round 4
// baseline (340.362 us; speedup 1.0000x reference)
//
#include <hip/hip_runtime.h>
#include <math.h>

// Problem constants
#define TT 9000          // samples per channel
#define DT 300           // crop length
#define KK 64            // crops per channel
#define NB 35            // band bins: rfft bins 7..41 (freqs 0.1*i, band 40/60..250/60)
#define KMIN 7
#define NCH 4096         // B*C channels
#define NPAIR (KK * NB)  // 2240 outputs per channel

// GEMM per channel: C[64 x 96] = A[64 x 320] * W[320 x 96]
//   A[m][k] = sig[off_m + k]   (k >= 300 rows of W are zero -> values don't matter)
//   W cols: n-tile 0..2 -> cos_j (j = nt*16 + col), n-tile 3..5 -> sin_j
// 16x16x32 bf16 MFMA, 10 K-steps, 6 N-tiles, 4 waves = 4 M-tiles of 16 crops.
// Mean-subtraction is a no-op for bins>=1; forward-norm 1/300 cancels in the
// unit-sum normalization.
//
// R4: no LDS at all. A is read straight from global (L1 captures the ~2.2x
// crop-overlap reuse within the block's channel); zero LDS + VGPR<=64 lifts
// occupancy from 4 to 8 blocks/CU and removes the staging barrier drain.

typedef __bf16 bf16;
typedef __attribute__((ext_vector_type(8))) __bf16 bf16x8;
typedef __attribute__((ext_vector_type(4))) float f32x4;

#define NFRAG_ELEMS (10 * 6 * 64 * 8)   // 30720 bf16 = 61440 B in d_ws

// W table in B-fragment order: flat idx ((kstep*6 + nt)*64 + lane)*8 + j
// B-frag layout (16x16x32): lane l holds B[k = kstep*32 + (l>>4)*8 + j][n = l&15]
__global__ void build_w(bf16* __restrict__ tab) {
    int i = blockIdx.x * blockDim.x + threadIdx.x;
    if (i >= NFRAG_ELEMS) return;
    int j    = i & 7;
    int l    = (i >> 3) & 63;
    int f    = i >> 9;           // frag index = kstep*6 + nt
    int nt   = f % 6;
    int ks   = f / 6;
    int quad = l >> 4;
    int c    = l & 15;
    int k    = ks * 32 + quad * 8 + j;   // time index 0..319
    int jf   = (nt % 3) * 16 + c;        // band bin index 0..47
    float v = 0.0f;
    if (jf <= NB - 1 && k < DT) {
        int bin = jf + KMIN;                       // rfft bin 7..41
        int ph  = (bin * k) % DT;                  // exact integer phase
        float ang = 0.02094395102393195f * (float)ph;  // 2*pi/300 * ph
        v = (nt >= 3) ? sinf(ang) : cosf(ang);
    }
    tab[i] = (bf16)v;
}

__global__ __launch_bounds__(256, 8) void st_mfma(
        const float* __restrict__ input,    // [NCH, TT] fp32
        const int*   __restrict__ offsets,  // [NCH, KK] int32
        const bf16*  __restrict__ tab,      // W in B-frag order
        float*       __restrict__ out) {    // [NCH, KK, NB] fp32
    const int bc   = blockIdx.x;
    const int tid  = threadIdx.x;
    const int w    = tid >> 6;    // wave = M-tile (16 crops)
    const int lane = tid & 63;
    const int quad = lane >> 4;
    const int c    = lane & 15;

    // Per-lane offset load (16 unique dwords per wave, L1-served).
    const int off = offsets[bc * KK + w * 16 + c];

    // A-frag source: lane holds A[m=c][k = ks*32 + quad*8 + j], j=0..7
    const float* sp = input + (size_t)bc * TT + off + quad * 8;

    const bf16x8* wt = (const bf16x8*)tab;

    f32x4 acc[6];
#pragma unroll
    for (int nt = 0; nt < 6; ++nt) acc[nt] = (f32x4){0.f, 0.f, 0.f, 0.f};

#pragma unroll
    for (int ks = 0; ks < 10; ++ks) {
        const float* p = sp + ks * 32;
        bf16x8 a;
        if (ks < 9) {
#pragma unroll
            for (int j = 0; j < 8; ++j) a[j] = (bf16)p[j];
        } else {
            // last k-step: k = 288 + quad*8 + j; k >= 300 lanes are multiplied
            // by zero W rows AND may be out of bounds on the last channel ->
            // predicate the load (exec-masked, no OOB access).
#pragma unroll
            for (int j = 0; j < 8; ++j) {
                int k = 288 + quad * 8 + j;
                a[j] = (k < DT) ? (bf16)p[j] : (bf16)0.0f;
            }
        }
#pragma unroll
        for (int nt = 0; nt < 6; ++nt) {
            bf16x8 b = wt[(ks * 6 + nt) * 64 + lane];
            acc[nt] = __builtin_amdgcn_mfma_f32_16x16x32_bf16(a, b, acc[nt], 0, 0, 0);
        }
    }

    // Epilogue, all in registers. C/D layout: col = lane&15, row = quad*4 + r.
    // cos_j in acc[i], sin_j in acc[i+3] (same lane), j = i*16 + c.
    float* o = out + (size_t)bc * NPAIR;
#pragma unroll
    for (int r = 0; r < 4; ++r) {
        float p0 = acc[0][r] * acc[0][r] + acc[3][r] * acc[3][r];  // j = c
        float p1 = acc[1][r] * acc[1][r] + acc[4][r] * acc[4][r];  // j = 16+c
        float p2 = acc[2][r] * acc[2][r] + acc[5][r] * acc[5][r];  // j = 32+c (c<=2)
        float s = p0 + p1 + ((c <= 2) ? p2 : 0.0f);
        // band sum across the 16 lanes of this quad (xor masks stay in-quad)
#pragma unroll
        for (int d = 1; d < 16; d <<= 1) s += __shfl_xor(s, d, 64);
        float rinv = 1.0f / s;
        int crop = w * 16 + quad * 4 + r;
        float* oc = o + crop * NB;
        oc[c] = p0 * rinv;
        oc[16 + c] = p1 * rinv;
        if (c <= 2) oc[32 + c] = p2 * rinv;
    }
}

extern "C" void kernel_launch(void* const* d_in, const int* in_sizes, int n_in,
                              void* d_out, int out_size, void* d_ws, size_t ws_size,
                              hipStream_t stream) {
    const float* input   = (const float*)d_in[0];  // [256,16,9000] fp32
    const int*   offsets = (const int*)d_in[1];    // [256,16,64] int32
    float*       out     = (float*)d_out;          // [256,16,64,35] fp32
    bf16*        tab     = (bf16*)d_ws;            // 61440 B

    // d_ws is re-poisoned before every timed launch -> rebuild table each call.
    build_w<<<(NFRAG_ELEMS + 255) / 256, 256, 0, stream>>>(tab);
    st_mfma<<<NCH, 256, 0, stream>>>(input, offsets, tab, out);
}

// Round 5
// 249.627 us; speedup vs baseline: 1.3635x; 1.3635x over previous
//
#include <hip/hip_runtime.h>
#include <math.h>

// Problem constants
#define TT 9000          // samples per channel
#define DT 300           // crop length
#define KK 64            // crops per channel
#define NB 35            // band bins: rfft bins 7..41 (freqs 0.1*i, band 40/60..250/60)
#define KMIN 7
#define NCH 4096         // B*C channels
#define NPAIR (KK * NB)  // 2240 outputs per channel

// GEMM per channel: C[64 x 96] = A[64 x 320] * W[320 x 96]
//   A[m][k] = sig[off_m + k]   (k >= 300 rows of W are zero)
//   W cols: n-tile 0..2 -> cos_j (j = nt*16 + col), n-tile 3..5 -> sin_j
// 16x16x32 bf16 MFMA, 10 K-steps, 6 N-tiles, 4 waves = 4 M-tiles of 16 crops.
// Mean-subtraction is a no-op for bins>=1; forward-norm 1/300 cancels in the
// unit-sum normalization.
//
// R5: LDS staging restored (R4 showed global A-gathers thrash L1/L2 and
// amplify writes 3.6x), but sig stored as bf16: 18 KB/block -> 8 blocks/CU
// = 32 waves/CU (2x R3). bf16 conversion moves to staging (same rounding).

typedef __bf16 bf16;
typedef __attribute__((ext_vector_type(4))) __bf16 bf16x4;
typedef __attribute__((ext_vector_type(8))) __bf16 bf16x8;
typedef __attribute__((ext_vector_type(4))) float f32x4;

#define NFRAG_ELEMS (10 * 6 * 64 * 8)   // 30720 bf16 = 61440 B in d_ws

// W table in B-fragment order: flat idx ((kstep*6 + nt)*64 + lane)*8 + j
// B-frag layout (16x16x32): lane l holds B[k = kstep*32 + (l>>4)*8 + j][n = l&15]
__global__ void build_w(bf16* __restrict__ tab) {
    int i = blockIdx.x * blockDim.x + threadIdx.x;
    if (i >= NFRAG_ELEMS) return;
    int j    = i & 7;
    int l    = (i >> 3) & 63;
    int f    = i >> 9;           // frag index = kstep*6 + nt
    int nt   = f % 6;
    int ks   = f / 6;
    int quad = l >> 4;
    int c    = l & 15;
    int k    = ks * 32 + quad * 8 + j;   // time index 0..319
    int jf   = (nt % 3) * 16 + c;        // band bin index 0..47
    float v = 0.0f;
    if (jf <= NB - 1 && k < DT) {
        int bin = jf + KMIN;                       // rfft bin 7..41
        int ph  = (bin * k) % DT;                  // exact integer phase
        float ang = 0.02094395102393195f * (float)ph;  // 2*pi/300 * ph
        v = (nt >= 3) ? sinf(ang) : cosf(ang);
    }
    tab[i] = (bf16)v;
}

__global__ __launch_bounds__(256, 8) void st_mfma(
        const float* __restrict__ input,    // [NCH, TT] fp32
        const int*   __restrict__ offsets,  // [NCH, KK] int32
        const bf16*  __restrict__ tab,      // W in B-frag order
        float*       __restrict__ out) {    // [NCH, KK, NB] fp32
    // bf16 signal + zero pad (reads reach off+319 <= 9018)
    __shared__ __align__(16) bf16 sig[TT + 32];

    const int bc   = blockIdx.x;
    const int tid  = threadIdx.x;

    // Stage channel into LDS as bf16 (coalesced float4 reads, b64 LDS writes)
    const float4* src = (const float4*)(input + (size_t)bc * TT);
    bf16x4* dst = (bf16x4*)sig;
#pragma unroll
    for (int i = 0; i < 9; ++i) {        // 9*256 = 2304 >= 2250
        int idx = tid + i * 256;
        if (idx < TT / 4) {
            float4 v = src[idx];
            bf16x4 h = {(bf16)v.x, (bf16)v.y, (bf16)v.z, (bf16)v.w};
            dst[idx] = h;
        }
    }
    if (tid < 32) sig[TT + tid] = (bf16)0.0f;
    __syncthreads();

    const int w    = tid >> 6;    // wave = M-tile (16 crops)
    const int lane = tid & 63;
    const int quad = lane >> 4;
    const int c    = lane & 15;

    // Per-lane offset (16 unique dwords per wave, L1-served)
    const int off = offsets[bc * KK + w * 16 + c];

    // A-frag: lane holds A[m=c][k = ks*32 + quad*8 + j], j=0..7
    const bf16* sp = sig + off + quad * 8;

    const bf16x8* wt = (const bf16x8*)tab;

    f32x4 acc[6];
#pragma unroll
    for (int nt = 0; nt < 6; ++nt) acc[nt] = (f32x4){0.f, 0.f, 0.f, 0.f};

#pragma unroll
    for (int ks = 0; ks < 10; ++ks) {
        const bf16* p = sp + ks * 32;
        bf16x8 a;
#pragma unroll
        for (int j = 0; j < 8; ++j) a[j] = p[j];
#pragma unroll
        for (int nt = 0; nt < 6; ++nt) {
            bf16x8 b = wt[(ks * 6 + nt) * 64 + lane];
            acc[nt] = __builtin_amdgcn_mfma_f32_16x16x32_bf16(a, b, acc[nt], 0, 0, 0);
        }
    }

    // Epilogue, all in registers. C/D layout: col = lane&15, row = quad*4 + r.
    // cos_j in acc[i], sin_j in acc[i+3] (same lane), j = i*16 + c.
    float* o = out + (size_t)bc * NPAIR;
#pragma unroll
    for (int r = 0; r < 4; ++r) {
        float p0 = acc[0][r] * acc[0][r] + acc[3][r] * acc[3][r];  // j = c
        float p1 = acc[1][r] * acc[1][r] + acc[4][r] * acc[4][r];  // j = 16+c
        float p2 = acc[2][r] * acc[2][r] + acc[5][r] * acc[5][r];  // j = 32+c (c<=2)
        float s = p0 + p1 + ((c <= 2) ? p2 : 0.0f);
        // band sum across the 16 lanes of this quad (xor masks stay in-quad)
#pragma unroll
        for (int d = 1; d < 16; d <<= 1) s += __shfl_xor(s, d, 64);
        float rinv = 1.0f / s;
        int crop = w * 16 + quad * 4 + r;
        float* oc = o + crop * NB;
        oc[c] = p0 * rinv;
        oc[16 + c] = p1 * rinv;
        if (c <= 2) oc[32 + c] = p2 * rinv;
    }
}

extern "C" void kernel_launch(void* const* d_in, const int* in_sizes, int n_in,
                              void* d_out, int out_size, void* d_ws, size_t ws_size,
                              hipStream_t stream) {
    const float* input   = (const float*)d_in[0];  // [256,16,9000] fp32
    const int*   offsets = (const int*)d_in[1];    // [256,16,64] int32
    float*       out     = (float*)d_out;          // [256,16,64,35] fp32
    bf16*        tab     = (bf16*)d_ws;            // 61440 B

    // d_ws is re-poisoned before every timed launch -> rebuild table each call.
    build_w<<<(NFRAG_ELEMS + 255) / 256, 256, 0, stream>>>(tab);
    st_mfma<<<NCH, 256, 0, stream>>>(input, offsets, tab, out);
}